// Round 8
// baseline (893.721 us; speedup 1.0000x reference)
//
#include <hip/hip_runtime.h>

#define INT_MAX_C 0x7fffffff

typedef __attribute__((ext_vector_type(8))) short s16x8;
typedef __attribute__((ext_vector_type(4))) float f32x4;
typedef __attribute__((ext_vector_type(16))) float f32x16;

// ---------------------------------------------------------------- label prep
// single block: init inv -> scatter -> gather labels (tiny work, 1 launch)
__global__ __launch_bounds__(1024) void k_prep(const int* __restrict__ yi,
                                               const int* __restrict__ tyi,
                                               int* __restrict__ inv,
                                               int* __restrict__ labels,
                                               int b, int s) {
  for (int j = threadIdx.x; j < s; j += 1024) inv[j] = INT_MAX_C;
  __syncthreads();
  for (int j = threadIdx.x; j < s; j += 1024) {
    int v = tyi[j];
    if (v >= 0 && v < s) atomicMin(&inv[v], j);
  }
  __syncthreads();
  for (int i = threadIdx.x; i < b; i += 1024) {
    int v = yi[i];
    int lab = 0;
    if (v >= 0 && v < s) { int p = inv[v]; if (p != INT_MAX_C) lab = p; }
    labels[i] = lab;
  }
}

// ---------------------------------------------------------------- Y norms (fallback path)
__global__ __launch_bounds__(256) void k_ynorm(const float* __restrict__ Y,
                                               float* __restrict__ invY, int f) {
  int j = blockIdx.x;
  const float* row = Y + (size_t)j * f;
  float ss = 0.f;
  for (int k = threadIdx.x * 4; k < f; k += 256 * 4) {
    float4 v = *(const float4*)(row + k);
    ss += v.x * v.x + v.y * v.y + v.z * v.z + v.w * v.w;
  }
  int lane = threadIdx.x & 63, wid = threadIdx.x >> 6;
#pragma unroll
  for (int o = 32; o > 0; o >>= 1) ss += __shfl_down(ss, o, 64);
  __shared__ float sh[4];
  if (lane == 0) sh[wid] = ss;
  __syncthreads();
  if (threadIdx.x == 0) {
    float tot = sh[0] + sh[1] + sh[2] + sh[3];
    invY[j] = 1.f / fmaxf(sqrtf(tot), 1e-8f);
  }
}

// ------------------------------------------- Z norms + sim at label (fallback path)
__global__ __launch_bounds__(256) void k_zrow(
    const float* __restrict__ Z, const float* __restrict__ Y,
    const int* __restrict__ labels, const float* __restrict__ invY,
    float* __restrict__ invZ, float* __restrict__ simL, int f) {
  int i = blockIdx.x;
  int lab = labels[i];
  const float* zr = Z + (size_t)i * f;
  const float* yr = Y + (size_t)lab * f;
  float ss = 0.f, dt = 0.f;
  for (int k = threadIdx.x * 4; k < f; k += 256 * 4) {
    float4 z = *(const float4*)(zr + k);
    float4 y = *(const float4*)(yr + k);
    ss += z.x * z.x + z.y * z.y + z.z * z.z + z.w * z.w;
    dt += z.x * y.x + z.y * y.y + z.z * y.z + z.w * y.w;
  }
  int lane = threadIdx.x & 63, wid = threadIdx.x >> 6;
#pragma unroll
  for (int o = 32; o > 0; o >>= 1) {
    ss += __shfl_down(ss, o, 64);
    dt += __shfl_down(dt, o, 64);
  }
  __shared__ float shs[4], shd[4];
  if (lane == 0) { shs[wid] = ss; shd[wid] = dt; }
  __syncthreads();
  if (threadIdx.x == 0) {
    float S = shs[0] + shs[1] + shs[2] + shs[3];
    float D = shd[0] + shd[1] + shd[2] + shd[3];
    float iz = 1.f / fmaxf(sqrtf(S), 1e-8f);
    invZ[i] = iz;
    simL[i] = D * iz * invY[lab];
  }
}

// ------------------------------------------------- split helpers
__device__ __forceinline__ uint rne_hi_bits(uint u) {
  return (u + 0x7fffu + ((u >> 16) & 1u)) & 0xffff0000u;
}

__device__ __forceinline__ void split_pack8(float4 a, float4 b, uint4& hi, uint4& lo) {
  float v[8] = {a.x, a.y, a.z, a.w, b.x, b.y, b.z, b.w};
  uint h[8], l[8];
#pragma unroll
  for (int i = 0; i < 8; ++i) {
    uint u = __float_as_uint(v[i]);
    uint rh = rne_hi_bits(u);
    h[i] = rh;
    float d = v[i] - __uint_as_float(rh);  // exact (Sterbenz)
    uint ud = __float_as_uint(d);
    l[i] = (ud + 0x7fffu + ((ud >> 16) & 1u));
  }
  hi = make_uint4((h[0] >> 16) | h[1], (h[2] >> 16) | h[3],
                  (h[4] >> 16) | h[5], (h[6] >> 16) | h[7]);
  lo = make_uint4((l[0] >> 16) | (l[1] & 0xffff0000u),
                  (l[2] >> 16) | (l[3] & 0xffff0000u),
                  (l[4] >> 16) | (l[5] & 0xffff0000u),
                  (l[6] >> 16) | (l[7] & 0xffff0000u));
}

// --------------------------------------------- merged panel pack kernel
// Z panel (128-row tiles): 16 KB/kc = [Ah 8K][Al 8K]; Y panel (160-row
// tiles): 20 KB/kc = [Bh 10K][Bl 10K]. row stride 64 B, chunk kq stored at
// (kq ^ ((row>>1)&3)). Z part also computes invZ and RAW dotL (no invY dep,
// so Z and Y packing are independent -> one kernel).
__global__ __launch_bounds__(256) void k_pack(const float* __restrict__ Z,
                                              const float* __restrict__ Y,
                                              const int* __restrict__ labels,
                                              char* __restrict__ Zpan,
                                              char* __restrict__ Ypan,
                                              float* __restrict__ invZ,
                                              float* __restrict__ dotL,
                                              float* __restrict__ invY,
                                              int s, int f, int nkc, int zblocks) {
  int lane = threadIdx.x & 63;
  int niter = f >> 9;
  if ((int)blockIdx.x < zblocks) {
    int r = blockIdx.x * 4 + (threadIdx.x >> 6);
    int rt = r >> 7, rl = r & 127;
    char* pan = Zpan + (size_t)rt * nkc * 16384;
    const float* row = Z + (size_t)r * f;
    int lab = labels[r];
    const float* yrow = Y + (size_t)lab * f;
    float ss = 0.f, dt = 0.f;
    for (int j = 0; j < niter; ++j) {
      int gq = lane + 64 * j;
      float4 v0 = *(const float4*)(row + gq * 8);
      float4 v1 = *(const float4*)(row + gq * 8 + 4);
      float4 y0 = *(const float4*)(yrow + gq * 8);
      float4 y1 = *(const float4*)(yrow + gq * 8 + 4);
      ss += v0.x * v0.x + v0.y * v0.y + v0.z * v0.z + v0.w * v0.w +
            v1.x * v1.x + v1.y * v1.y + v1.z * v1.z + v1.w * v1.w;
      dt += v0.x * y0.x + v0.y * y0.y + v0.z * y0.z + v0.w * y0.w +
            v1.x * y1.x + v1.y * y1.y + v1.z * y1.z + v1.w * y1.w;
      uint4 h, l;
      split_pack8(v0, v1, h, l);
      int kc = gq >> 2, kq = gq & 3;
      size_t off = (size_t)kc * 16384 + rl * 64 + ((kq ^ ((rl >> 1) & 3)) << 4);
      *(uint4*)(pan + off) = h;
      *(uint4*)(pan + off + 8192) = l;
    }
#pragma unroll
    for (int o = 32; o > 0; o >>= 1) {
      ss += __shfl_down(ss, o, 64);
      dt += __shfl_down(dt, o, 64);
    }
    if (lane == 0) {
      invZ[r] = 1.f / fmaxf(sqrtf(ss), 1e-8f);
      dotL[r] = dt;
    }
  } else {
    int r = (blockIdx.x - zblocks) * 4 + (threadIdx.x >> 6);
    int ct = r / 160, rl = r % 160;
    char* pan = Ypan + (size_t)ct * nkc * 20480;
    const float* row = Y + (size_t)r * f;
    const bool ok = r < s;
    float ss = 0.f;
    for (int j = 0; j < niter; ++j) {
      int gq = lane + 64 * j;
      float4 v0 = {}, v1 = {};
      if (ok) {
        v0 = *(const float4*)(row + gq * 8);
        v1 = *(const float4*)(row + gq * 8 + 4);
      }
      ss += v0.x * v0.x + v0.y * v0.y + v0.z * v0.z + v0.w * v0.w +
            v1.x * v1.x + v1.y * v1.y + v1.z * v1.z + v1.w * v1.w;
      uint4 h, l;
      split_pack8(v0, v1, h, l);
      int kc = gq >> 2, kq = gq & 3;
      size_t off = (size_t)kc * 20480 + rl * 64 + ((kq ^ ((rl >> 1) & 3)) << 4);
      *(uint4*)(pan + off) = h;
      *(uint4*)(pan + off + 10240) = l;
    }
    if (ok) {
#pragma unroll
      for (int o = 32; o > 0; o >>= 1) ss += __shfl_down(ss, o, 64);
      if (lane == 0) invY[r] = 1.f / fmaxf(sqrtf(ss), 1e-8f);
    }
  }
}

// ------------------------------------------------- DMA helper
__device__ __forceinline__ void dma16(const void* g, void* l) {
  __builtin_amdgcn_global_load_lds((const __attribute__((address_space(1))) unsigned int*)g,
                                   (__attribute__((address_space(3))) unsigned int*)l,
                                   16, 0, 0);
}

// ------------------------------------------------- main GEMM (panel path)
// TM=128, TN=160, BK=32. 4 waves, each owns 32x160 (5 tiles of 32x32x16).
// Single LDS buffer 36 KB (R7-proven 3-waves/SIMD occupancy): acc = 5 x 16
// = 80 AGPR. 32x32x16 MFMA: 30 instr/wave/iter vs 60 (16x16) -> less issue
// churn, +15% pipe rate. Fused finalize via device-scope ticket.
// A/B frag: m|n = lane&31, k = (lane>>5)*8 + j. C/D (m74/m101):
// col = lane&31, row = (reg&3) + 8*(reg>>2) + 4*(lane>>5).
__global__ __launch_bounds__(256, 3) void k_gemm_rank_pan(
    const char* __restrict__ Zpan, const char* __restrict__ Ypan,
    const float* __restrict__ invZ, const float* __restrict__ invY,
    const float* __restrict__ dotL, const int* __restrict__ labels,
    int* __restrict__ rank, int* __restrict__ ticket, float* __restrict__ out,
    int b, int s, int nkc, int nblocks) {
  __shared__ ushort SMu[18432];  // 36864 B: [Ah 8K][Al 8K][Bh 10K][Bl 10K]
  char* SMb = (char*)SMu;
  __shared__ float sL[128], sIz[128];
  __shared__ int sLab[128], sCnt[128];
  __shared__ int sLast;
  __shared__ int s1[4], s5[4];

  const int t = threadIdx.x;
  const int row0 = blockIdx.x * 128;   // x = row tile (fast) -> L3 reuse of Zpan
  const int col0 = blockIdx.y * 160;

  if (t < 128) {
    int gi = row0 + t;
    int lab = labels[gi];
    float iz = invZ[gi];
    sIz[t] = iz;
    sLab[t] = lab;
    sL[t] = dotL[gi] * iz * invY[lab];  // same multiply order as old simL
    sCnt[t] = 0;
  }

  const char* srcA = Zpan + (size_t)blockIdx.x * nkc * 16384 + t * 16;
  const char* srcB = Ypan + (size_t)blockIdx.y * nkc * 20480 + t * 16;

  const int lane = t & 63;
  const int wv = t >> 6;
  const int ln = lane & 31;   // m (A-row) / n (B-col) within 32-tile
  const int h  = lane >> 5;   // k-half selector
  const int sw = (ln >> 1) & 3;  // swizzle ((row>>1)&3; tile bases are mult of 32)

  int aoff[2], boff[2];
#pragma unroll
  for (int kw = 0; kw < 2; ++kw) {
    int ch = (((kw << 1) | h) ^ sw) << 4;
    aoff[kw] = (wv * 32 + ln) * 64 + ch;
    boff[kw] = 16384 + ln * 64 + ch;
  }

  f32x16 acc[5] = {};

  for (int kt = 0; kt < nkc; ++kt) {
    __syncthreads();  // prior-iter fragment reads complete
#pragma unroll
    for (int j = 0; j < 4; ++j) dma16(srcA + j * 4096, SMb + j * 4096 + t * 16);
#pragma unroll
    for (int j = 0; j < 5; ++j) dma16(srcB + j * 4096, SMb + 16384 + j * 4096 + t * 16);
    srcA += 16384; srcB += 20480;
    __syncthreads();  // DMA drained

#pragma unroll
    for (int kw = 0; kw < 2; ++kw) {
      s16x8 ah = *(const s16x8*)(SMb + aoff[kw]);
      s16x8 al = *(const s16x8*)(SMb + aoff[kw] + 8192);
#pragma unroll
      for (int cc = 0; cc < 5; ++cc) {
        s16x8 bh = *(const s16x8*)(SMb + boff[kw] + cc * 2048);
        s16x8 bl = *(const s16x8*)(SMb + boff[kw] + cc * 2048 + 10240);
        acc[cc] = __builtin_amdgcn_mfma_f32_32x32x16_bf16(ah, bh, acc[cc], 0, 0, 0);
        acc[cc] = __builtin_amdgcn_mfma_f32_32x32x16_bf16(ah, bl, acc[cc], 0, 0, 0);
        acc[cc] = __builtin_amdgcn_mfma_f32_32x32x16_bf16(al, bh, acc[cc], 0, 0, 0);
      }
    }
  }

  // ---- epilogue: rank counting
  float iY[5];
#pragma unroll
  for (int cc = 0; cc < 5; ++cc) {
    int gj = col0 + cc * 32 + ln;
    iY[cc] = (gj < s) ? invY[gj] : 0.f;
  }

#pragma unroll
  for (int reg = 0; reg < 16; ++reg) {
    int li = wv * 32 + (reg & 3) + 8 * (reg >> 2) + 4 * h;
    float iz = sIz[li], sl = sL[li];
    int lab = sLab[li];
    int cnt = 0;
#pragma unroll
    for (int cc = 0; cc < 5; ++cc) {
      int gj = col0 + cc * 32 + ln;
      if (gj < s && gj != lab) {
        float sim = acc[cc][reg] * iz * iY[cc];
        cnt += (sim > sl || (sim == sl && gj < lab)) ? 1 : 0;
      }
    }
    cnt += __shfl_down(cnt, 16, 32);
    cnt += __shfl_down(cnt, 8, 32);
    cnt += __shfl_down(cnt, 4, 32);
    cnt += __shfl_down(cnt, 2, 32);
    cnt += __shfl_down(cnt, 1, 32);
    if (ln == 0 && cnt) atomicAdd(&sCnt[li], cnt);
  }
  __syncthreads();
  if (t < 128) {
    int gi = row0 + t;
    if (sCnt[t]) atomicAdd(&rank[gi], sCnt[t]);
  }
  __syncthreads();

  // ---- fused finalize: last block reduces rank -> accuracies
  if (t == 0) {
    __threadfence();
    int v = atomicAdd(ticket, 1);
    sLast = (v == nblocks - 1) ? 1 : 0;
  }
  __syncthreads();
  if (sLast) {
    __threadfence();
    int c1 = 0, c5 = 0;
    for (int i = t; i < b; i += 256) {
      int r = atomicAdd(&rank[i], 0);  // coherent device-scope read
      c1 += (r < 1);
      c5 += (r < 5);
    }
    int wid = t >> 6;
#pragma unroll
    for (int o = 32; o > 0; o >>= 1) {
      c1 += __shfl_down(c1, o, 64);
      c5 += __shfl_down(c5, o, 64);
    }
    if (lane == 0) { s1[wid] = c1; s5[wid] = c5; }
    __syncthreads();
    if (t == 0) {
      int t1 = s1[0] + s1[1] + s1[2] + s1[3];
      int t5 = s5[0] + s5[1] + s5[2] + s5[3];
      out[0] = (float)t1 / (float)b;
      out[1] = (float)t5 / (float)b;
    }
  }
}

// ------------------------------------------------- fallback GEMM (R2-proven)
#define TMF 128
#define TNF 128
#define BKF 32
#define SKF 40

__global__ __launch_bounds__(256) void k_gemm_rank_v2(
    const float* __restrict__ Z, const float* __restrict__ Y,
    const float* __restrict__ invZ, const float* __restrict__ invY,
    const float* __restrict__ simL, const int* __restrict__ labels,
    int* __restrict__ rank, int b, int s, int f) {
  __shared__ short Ah[TMF * SKF], Al[TMF * SKF], Bh[TNF * SKF], Bl[TNF * SKF];
  __shared__ float sL[TMF], sIz[TMF];
  __shared__ int sLab[TMF], sCnt[TMF];

  const int t = threadIdx.x;
  const int row0 = blockIdx.y * TMF;
  const int col0 = blockIdx.x * TNF;

  if (t < TMF) {
    int gi = row0 + t;
    if (gi < b) { sL[t] = simL[gi]; sIz[t] = invZ[gi]; sLab[t] = labels[gi]; }
    else        { sL[t] = 0.f;      sIz[t] = 0.f;      sLab[t] = -1; }
    sCnt[t] = 0;
  }

  const int srow  = t >> 1;
  const int skoff = (t & 1) << 4;
  const bool zok = (row0 + srow) < b;
  const bool yok = (col0 + srow) < s;
  const float* zp = Z + (size_t)(row0 + srow) * f + skoff;
  const float* yp = Y + (size_t)(col0 + srow) * f + skoff;

  const int lane = t & 63;
  const int wv = t >> 6;
  const int wr = wv >> 1, wc = wv & 1;
  const int fm = lane & 15, quad = lane >> 4;

  f32x4 acc[4][4] = {};

  for (int kt = 0; kt < f; kt += BKF) {
    float4 z0 = {}, z1 = {}, z2 = {}, z3 = {};
    float4 y0 = {}, y1 = {}, y2 = {}, y3 = {};
    if (zok) {
      z0 = *(const float4*)(zp + 0); z1 = *(const float4*)(zp + 4);
      z2 = *(const float4*)(zp + 8); z3 = *(const float4*)(zp + 12);
    }
    if (yok) {
      y0 = *(const float4*)(yp + 0); y1 = *(const float4*)(yp + 4);
      y2 = *(const float4*)(yp + 8); y3 = *(const float4*)(yp + 12);
    }
    zp += BKF; yp += BKF;

    __syncthreads();

    uint4 h, l;
    split_pack8(z0, z1, h, l);
    *(uint4*)(Ah + srow * SKF + skoff)     = h;
    *(uint4*)(Al + srow * SKF + skoff)     = l;
    split_pack8(z2, z3, h, l);
    *(uint4*)(Ah + srow * SKF + skoff + 8) = h;
    *(uint4*)(Al + srow * SKF + skoff + 8) = l;
    split_pack8(y0, y1, h, l);
    *(uint4*)(Bh + srow * SKF + skoff)     = h;
    *(uint4*)(Bl + srow * SKF + skoff)     = l;
    split_pack8(y2, y3, h, l);
    *(uint4*)(Bh + srow * SKF + skoff + 8) = h;
    *(uint4*)(Bl + srow * SKF + skoff + 8) = l;

    __syncthreads();

    s16x8 ah[4], al4[4], bh[4], bl4[4];
#pragma unroll
    for (int rr = 0; rr < 4; ++rr) {
      int ar = wr * 64 + rr * 16 + fm;
      ah[rr]  = *(const s16x8*)(Ah + ar * SKF + quad * 8);
      al4[rr] = *(const s16x8*)(Al + ar * SKF + quad * 8);
    }
#pragma unroll
    for (int cc = 0; cc < 4; ++cc) {
      int br = wc * 64 + cc * 16 + fm;
      bh[cc]  = *(const s16x8*)(Bh + br * SKF + quad * 8);
      bl4[cc] = *(const s16x8*)(Bl + br * SKF + quad * 8);
    }
#pragma unroll
    for (int rr = 0; rr < 4; ++rr)
#pragma unroll
      for (int cc = 0; cc < 4; ++cc) {
        acc[rr][cc] = __builtin_amdgcn_mfma_f32_16x16x32_bf16(ah[rr],  bh[cc],  acc[rr][cc], 0, 0, 0);
        acc[rr][cc] = __builtin_amdgcn_mfma_f32_16x16x32_bf16(ah[rr],  bl4[cc], acc[rr][cc], 0, 0, 0);
        acc[rr][cc] = __builtin_amdgcn_mfma_f32_16x16x32_bf16(al4[rr], bh[cc],  acc[rr][cc], 0, 0, 0);
      }
  }

  float iYc[4]; int gjc[4];
#pragma unroll
  for (int c = 0; c < 4; ++c) {
    int gj = col0 + wc * 64 + c * 16 + fm;
    gjc[c] = gj;
    iYc[c] = (gj < s) ? invY[gj] : 0.f;
  }

#pragma unroll
  for (int rr = 0; rr < 4; ++rr) {
#pragma unroll
    for (int reg = 0; reg < 4; ++reg) {
      int li = wr * 64 + rr * 16 + quad * 4 + reg;
      int gi = row0 + li;
      int cnt = 0;
      if (gi < b) {
        float iz = sIz[li], sl = sL[li];
        int lab = sLab[li];
#pragma unroll
        for (int c = 0; c < 4; ++c) {
          int gj = gjc[c];
          if (gj < s && gj != lab) {
            float sim = acc[rr][c][reg] * iz * iYc[c];
            cnt += (sim > sl || (sim == sl && gj < lab)) ? 1 : 0;
          }
        }
      }
      cnt += __shfl_down(cnt, 8, 16);
      cnt += __shfl_down(cnt, 4, 16);
      cnt += __shfl_down(cnt, 2, 16);
      cnt += __shfl_down(cnt, 1, 16);
      if (fm == 0 && cnt) atomicAdd(&sCnt[li], cnt);
    }
  }
  __syncthreads();
  if (t < TMF) {
    int gi = row0 + t;
    if (gi < b && sCnt[t]) atomicAdd(&rank[gi], sCnt[t]);
  }
}

// ---------------------------------------------------------------- finalize (fallback)
__global__ __launch_bounds__(256) void k_final(const int* __restrict__ rank,
                                               float* __restrict__ out, int b) {
  int c1 = 0, c5 = 0;
  for (int i = threadIdx.x; i < b; i += 256) {
    int r = rank[i];
    c1 += (r < 1);
    c5 += (r < 5);
  }
  int lane = threadIdx.x & 63, wid = threadIdx.x >> 6;
#pragma unroll
  for (int o = 32; o > 0; o >>= 1) {
    c1 += __shfl_down(c1, o, 64);
    c5 += __shfl_down(c5, o, 64);
  }
  __shared__ int s1[4], s5[4];
  if (lane == 0) { s1[wid] = c1; s5[wid] = c5; }
  __syncthreads();
  if (threadIdx.x == 0) {
    int t1 = s1[0] + s1[1] + s1[2] + s1[3];
    int t5 = s5[0] + s5[1] + s5[2] + s5[3];
    out[0] = (float)t1 / (float)b;
    out[1] = (float)t5 / (float)b;
  }
}

// ---------------------------------------------------------------- launch
extern "C" void kernel_launch(void* const* d_in, const int* in_sizes, int n_in,
                              void* d_out, int out_size, void* d_ws, size_t ws_size,
                              hipStream_t stream) {
  const float* Z  = (const float*)d_in[0];
  const int* yi   = (const int*)d_in[1];
  const float* Y  = (const float*)d_in[2];
  const int* tyi  = (const int*)d_in[3];
  const int b = in_sizes[1];
  const int s = in_sizes[3];
  const int f = in_sizes[0] / b;
  float* out = (float*)d_out;

  char* p = (char*)d_ws;
  size_t used = 0;
  auto alloc = [&](size_t bytes) {
    char* r = p;
    size_t a = (bytes + 255) & ~(size_t)255;
    p += a; used += a;
    return r;
  };
  int* inv     = (int*)alloc((size_t)s * 4);
  int* labels  = (int*)alloc((size_t)b * 4);
  int* rank    = (int*)alloc((size_t)b * 4 + 4);  // + ticket
  int* ticket  = rank + b;
  float* invY  = (float*)alloc((size_t)s * 4);
  float* invZ  = (float*)alloc((size_t)b * 4);
  float* dotL  = (float*)alloc((size_t)b * 4);   // raw dot (panel) / simL (fallback)

  const int nkc = f >> 5;                  // k-chunks of 32
  const int nrt = b / 128;                 // Z row tiles
  const int nct = (s + 159) / 160;         // Y col tiles (padded)
  const int rows_pad = nct * 160;
  const size_t zpan_sz = (size_t)nrt * nkc * 16384;
  const size_t ypan_sz = (size_t)nct * nkc * 20480;
  const size_t need = used + zpan_sz + ypan_sz + 1024;
  const bool use_pan = (ws_size >= need) && (b % 128 == 0) && (f % 512 == 0);

  hipMemsetAsync(rank, 0, (size_t)b * 4 + 4, stream);
  k_prep<<<1, 1024, 0, stream>>>(yi, tyi, inv, labels, b, s);

  if (use_pan) {
    char* Zpan = (char*)alloc(zpan_sz);
    char* Ypan = (char*)alloc(ypan_sz);
    const int zblocks = b / 4;
    const int yblocks = rows_pad / 4;
    k_pack<<<zblocks + yblocks, 256, 0, stream>>>(Z, Y, labels, Zpan, Ypan,
                                                  invZ, dotL, invY, s, f, nkc,
                                                  zblocks);
    dim3 grid(nrt, nct);  // x = row tile (fast) -> concurrent blocks share col tile
    k_gemm_rank_pan<<<grid, 256, 0, stream>>>(Zpan, Ypan, invZ, invY, dotL,
                                              labels, rank, ticket, out,
                                              b, s, nkc, nrt * nct);
  } else {
    k_ynorm<<<s, 256, 0, stream>>>(Y, invY, f);
    k_zrow<<<b, 256, 0, stream>>>(Z, Y, labels, invY, invZ, dotL, f);
    dim3 grid((s + TNF - 1) / TNF, (b + TMF - 1) / TMF);
    k_gemm_rank_v2<<<grid, 256, 0, stream>>>(Z, Y, invZ, invY, dotL, labels,
                                             rank, b, s, f);
    k_final<<<1, 256, 0, stream>>>(rank, out, b);
  }
}